// Round 1
// baseline (2738.836 us; speedup 1.0000x reference)
//
#include <hip/hip_runtime.h>

typedef __bf16 bf16;
typedef bf16 bf16x8 __attribute__((ext_vector_type(8)));
typedef float f32x4 __attribute__((ext_vector_type(4)));

#define NB 256     // batch
#define TS 64      // timesteps
#define DD 1024    // input dim
#define HH 1024    // hidden
#define KTOT 3072  // D + 2H (fused GEMM K)
#define NOUT 4096  // 4H
#define KTILES 96  // KTOT/32
#define NTILES 256 // NOUT/16

// ---------------------------------------------------------------------------
// Operand tile format: 16(rows/cols) x 32(k) fragment tiles of 512 bf16 (1KB).
// Within a tile, lane l owns 8 consecutive-k elements at byte offset l*16:
//   element (l, j):  row/col = base + (l&15),  k = kbase + (l>>4)*8 + j
// This matches the mfma_f32_16x16x32_bf16 A/B operand layout, makes the
// global->LDS stage a linear copy, and makes ds_read_b128 conflict-free.
// ---------------------------------------------------------------------------

static __device__ __forceinline__ void aop_store(bf16* __restrict__ Aop, int n, int k, float v) {
  const int mt = n >> 4;
  const int kt = k >> 5;
  const int off = (mt * KTILES + kt) * 512 + ((k >> 3) & 3) * 128 + (n & 15) * 8 + (k & 7);
  Aop[off] = (bf16)v;
}

// Convert [Wx; Wh; Wattn] (3072 x 4096 f32, stacked on K) into tiled bf16.
__global__ __launch_bounds__(256) void convert_w(const float* __restrict__ Wx,
                                                 const float* __restrict__ Wh,
                                                 const float* __restrict__ Wattn,
                                                 bf16* __restrict__ Wt) {
  const int gid = blockIdx.x * 256 + threadIdx.x;  // one 16B chunk per thread
  const int tile = gid >> 6;                       // 0..24575
  const int l = gid & 63;
  const int ntile = tile / KTILES;
  const int ktile = tile % KTILES;
  const int n = ntile * 16 + (l & 15);
  const int k0 = ktile * 32 + (l >> 4) * 8;
  bf16x8 ovec;
#pragma unroll
  for (int j = 0; j < 8; ++j) {
    const int k = k0 + j;
    float v;
    if (k < DD)            v = Wx[(size_t)k * NOUT + n];
    else if (k < DD + HH)  v = Wh[(size_t)(k - DD) * NOUT + n];
    else                   v = Wattn[(size_t)(k - DD - HH) * NOUT + n];
    ovec[j] = (bf16)v;
  }
  *(bf16x8*)(Wt + (size_t)tile * 512 + l * 8) = ovec;
}

// Attention over 16 positions + pack [xt | h | attn] into tiled bf16 operand.
// One block per n, 256 threads; each thread owns units u = tid + q*256.
static __device__ void attn_pack(int n, int tid, const float hq[4],
                                 const float* __restrict__ A,
                                 const float* __restrict__ xt,
                                 bf16* __restrict__ Aop,
                                 float* __restrict__ red,   // [64] LDS
                                 float* __restrict__ w_sh)  // [16] LDS
{
  const float* An = A + (size_t)n * (HH * 16);
  float s[16];
#pragma unroll
  for (int p = 0; p < 16; ++p) s[p] = 0.f;
#pragma unroll
  for (int q = 0; q < 4; ++q) {
    const int u = tid + q * 256;
    const float hv = hq[q];
    const float* a = An + (size_t)u * 16;
#pragma unroll
    for (int p = 0; p < 16; ++p) s[p] = fmaf(hv, a[p], s[p]);
  }
  // 64-lane butterfly reduce of the 16 partial scores
#pragma unroll
  for (int off = 1; off < 64; off <<= 1) {
#pragma unroll
    for (int p = 0; p < 16; ++p) s[p] += __shfl_xor(s[p], off, 64);
  }
  const int lane = tid & 63, wid = tid >> 6;
  if (lane == 0) {
#pragma unroll
    for (int p = 0; p < 16; ++p) red[wid * 16 + p] = s[p];
  }
  __syncthreads();
  if (tid == 0) {  // softmax over 16 positions (serial: tiny)
    float sc[16];
    float m = -3.0e38f;
#pragma unroll
    for (int p = 0; p < 16; ++p) {
      sc[p] = (red[p] + red[16 + p] + red[32 + p] + red[48 + p]) * 0.03125f;  // 1/sqrt(1024)
      m = fmaxf(m, sc[p]);
    }
    float sum = 0.f;
#pragma unroll
    for (int p = 0; p < 16; ++p) {
      const float e = expf(sc[p] - m);
      sc[p] = e;
      sum += e;
    }
    const float inv = 1.f / sum;
#pragma unroll
    for (int p = 0; p < 16; ++p) w_sh[p] = sc[p] * inv;
  }
  __syncthreads();
#pragma unroll
  for (int q = 0; q < 4; ++q) {
    const int u = tid + q * 256;
    const float* a = An + (size_t)u * 16;
    float acc = 0.f;
#pragma unroll
    for (int p = 0; p < 16; ++p) acc = fmaf(a[p], w_sh[p], acc);
    aop_store(Aop, n, u, xt[u]);            // x_{t}
    aop_store(Aop, n, HH + u, hq[q]);       // h
    aop_store(Aop, n, 2 * HH + u, acc);     // attn
  }
}

// h0 = mean(A, axis=(2,3)); c0 = h0; pack operand for step 0.
__global__ __launch_bounds__(256) void init_kernel(const float* __restrict__ A,
                                                   const float* __restrict__ x,
                                                   float* __restrict__ c_ws,
                                                   bf16* __restrict__ Aop) {
  __shared__ float red[64];
  __shared__ float w_sh[16];
  const int n = blockIdx.x, tid = threadIdx.x;
  const float* An = A + (size_t)n * (HH * 16);
  float hq[4];
#pragma unroll
  for (int q = 0; q < 4; ++q) {
    const int u = tid + q * 256;
    const float* a = An + (size_t)u * 16;
    float sum = 0.f;
#pragma unroll
    for (int p = 0; p < 16; ++p) sum += a[p];
    hq[q] = sum * 0.0625f;
    c_ws[n * HH + u] = hq[q];
  }
  attn_pack(n, tid, hq, A, x + (size_t)n * TS * DD, Aop, red, w_sh);
}

// LSTM gates + output write + fused next-step attention/packing.
__global__ __launch_bounds__(256) void cell_kernel(const float* __restrict__ preact,
                                                   float* __restrict__ c_ws,
                                                   const float* __restrict__ A,
                                                   const float* __restrict__ x,
                                                   bf16* __restrict__ Aop,
                                                   float* __restrict__ out,
                                                   const int t) {
  __shared__ float red[64];
  __shared__ float w_sh[16];
  const int n = blockIdx.x, tid = threadIdx.x;
  const float* pr = preact + (size_t)n * NOUT;
  float hq[4];
#pragma unroll
  for (int q = 0; q < 4; ++q) {
    const int u = tid + q * 256;
    const float ai = pr[u];
    const float af = pr[HH + u];
    const float ao = pr[2 * HH + u];
    const float ag = pr[3 * HH + u];
    const float cold = c_ws[n * HH + u];
    const float si = 1.f / (1.f + expf(-ai));
    const float sf = 1.f / (1.f + expf(-af));
    const float so = 1.f / (1.f + expf(-ao));
    const float cn = sf * cold + si * tanhf(ag);
    const float hn = so * tanhf(cn);
    c_ws[n * HH + u] = cn;
    out[((size_t)n * TS + t) * HH + u] = hn;
    hq[q] = hn;
  }
  if (t == TS - 1) return;  // uniform exit: no pack needed after last step
  attn_pack(n, tid, hq, A, x + ((size_t)n * TS + (t + 1)) * DD, Aop, red, w_sh);
}

// preact(256x4096) = Aop(256x3072) @ Wt(3072x4096) + bias, bf16 MFMA.
// 64x64 tile per wg, 4 waves (2x2 of 32x32), BK=64, reg-staged LDS double buffer.
__global__ __launch_bounds__(256) void gemm_kernel(const bf16* __restrict__ Aop,
                                                   const bf16* __restrict__ Wt,
                                                   const float* __restrict__ bias,
                                                   float* __restrict__ preact) {
  __shared__ __align__(16) bf16 lds[2][16 * 512];  // 16 tiles x 1KB per buffer
  const int b = blockIdx.x;
  // XCD-aware map: XCD x (b%8) gets col-tiles [8x, 8x+8) over all 4 row-tiles,
  // so each XCD's 3MB weight slice stays L2-resident across all 64 steps.
  const int xcd = b & 7, m = b >> 3;
  const int rt = m & 3;                 // row tile (64 rows)
  const int ct = xcd * 8 + (m >> 2);    // col tile (64 cols)
  const int tid = threadIdx.x;
  const int lane = tid & 63, wid = tid >> 6;
  const int wr = wid >> 1, wc = wid & 1;

  // staging: thread handles tile-slots s = wid + q*4; slot s<8: A, else B.
  const bf16* gsrc[4];
  int ldsoff[4];
#pragma unroll
  for (int q = 0; q < 4; ++q) {
    const int s = wid + q * 4;
    ldsoff[q] = s * 512 + lane * 8;
    if (s < 8) {
      const int mt = rt * 4 + (s >> 1);
      gsrc[q] = Aop + ((size_t)mt * KTILES + (s & 1)) * 512 + lane * 8;
    } else {
      const int nt = ct * 4 + ((s - 8) >> 1);
      gsrc[q] = Wt + ((size_t)nt * KTILES + (s & 1)) * 512 + lane * 8;
    }
  }

  f32x4 acc[2][2];
#pragma unroll
  for (int i = 0; i < 2; ++i)
#pragma unroll
    for (int j = 0; j < 2; ++j) acc[i][j] = (f32x4){0.f, 0.f, 0.f, 0.f};

  const int aoff0 = ((wr * 2 + 0) * 2) * 512 + lane * 8;
  const int aoff1 = ((wr * 2 + 1) * 2) * 512 + lane * 8;
  const int boff0 = (8 + (wc * 2 + 0) * 2) * 512 + lane * 8;
  const int boff1 = (8 + (wc * 2 + 1) * 2) * 512 + lane * 8;

  bf16x8 regs[4];
#pragma unroll
  for (int q = 0; q < 4; ++q) { regs[q] = *(const bf16x8*)gsrc[q]; gsrc[q] += 1024; }
#pragma unroll
  for (int q = 0; q < 4; ++q) *(bf16x8*)&lds[0][ldsoff[q]] = regs[q];

  for (int t = 0; t < 48; ++t) {
    __syncthreads();  // buf[t&1] writes visible to all waves
    if (t < 47) {     // issue next-tile loads AFTER the barrier: latency hides under compute
#pragma unroll
      for (int q = 0; q < 4; ++q) { regs[q] = *(const bf16x8*)gsrc[q]; gsrc[q] += 1024; }
    }
    const bf16* buf = lds[t & 1];
#pragma unroll
    for (int ks = 0; ks < 2; ++ks) {
      const bf16x8 a0 = *(const bf16x8*)(buf + aoff0 + ks * 512);
      const bf16x8 a1 = *(const bf16x8*)(buf + aoff1 + ks * 512);
      const bf16x8 b0 = *(const bf16x8*)(buf + boff0 + ks * 512);
      const bf16x8 b1 = *(const bf16x8*)(buf + boff1 + ks * 512);
      acc[0][0] = __builtin_amdgcn_mfma_f32_16x16x32_bf16(a0, b0, acc[0][0], 0, 0, 0);
      acc[0][1] = __builtin_amdgcn_mfma_f32_16x16x32_bf16(a0, b1, acc[0][1], 0, 0, 0);
      acc[1][0] = __builtin_amdgcn_mfma_f32_16x16x32_bf16(a1, b0, acc[1][0], 0, 0, 0);
      acc[1][1] = __builtin_amdgcn_mfma_f32_16x16x32_bf16(a1, b1, acc[1][1], 0, 0, 0);
    }
    if (t < 47) {  // write other buffer; barrier at top of next iter orders vs readers
#pragma unroll
      for (int q = 0; q < 4; ++q) *(bf16x8*)&lds[(t + 1) & 1][ldsoff[q]] = regs[q];
    }
  }

  // epilogue: C/D layout col=lane&15, row=(lane>>4)*4+r  [m89-verified]
#pragma unroll
  for (int i = 0; i < 2; ++i) {
#pragma unroll
    for (int j = 0; j < 2; ++j) {
      const int row0 = rt * 64 + wr * 32 + i * 16 + (lane >> 4) * 4;
      const int col = ct * 64 + wc * 32 + j * 16 + (lane & 15);
      const float bc = bias[col];
#pragma unroll
      for (int r = 0; r < 4; ++r)
        preact[(size_t)(row0 + r) * NOUT + col] = acc[i][j][r] + bc;
    }
  }
}

// ---------------------------------------------------------------------------
// ws layout (bytes):
//   [0, 25165824)            Wt      bf16 tiled weights (3072x4096)
//   [25165824, 26738688)     Aop     bf16 tiled operand (256x3072)
//   [26738688, 30932992)     preact  f32 (256x4096)
//   [30932992, 31981568)     c       f32 (256x1024)
// total ~31 MB
// ---------------------------------------------------------------------------
extern "C" void kernel_launch(void* const* d_in, const int* in_sizes, int n_in,
                              void* d_out, int out_size, void* d_ws, size_t ws_size,
                              hipStream_t stream) {
  const float* x     = (const float*)d_in[0];
  const float* A     = (const float*)d_in[1];
  const float* Wx    = (const float*)d_in[2];
  const float* Wh    = (const float*)d_in[3];
  const float* Wattn = (const float*)d_in[4];
  const float* bias  = (const float*)d_in[5];
  float* out = (float*)d_out;
  char* ws = (char*)d_ws;
  bf16* Wt      = (bf16*)(ws + 0);
  bf16* Aop     = (bf16*)(ws + 25165824);
  float* preact = (float*)(ws + 26738688);
  float* c_ws   = (float*)(ws + 30932992);

  convert_w<<<6144, 256, 0, stream>>>(Wx, Wh, Wattn, Wt);
  init_kernel<<<NB, 256, 0, stream>>>(A, x, c_ws, Aop);
  for (int t = 0; t < TS; ++t) {
    gemm_kernel<<<NB, 256, 0, stream>>>(Aop, Wt, bias, preact);
    cell_kernel<<<NB, 256, 0, stream>>>(preact, c_ws, A, x, Aop, out, t);
  }
}

// Round 2
// 2605.844 us; speedup vs baseline: 1.0510x; 1.0510x over previous
//
#include <hip/hip_runtime.h>

typedef __bf16 bf16;
typedef bf16 bf16x8 __attribute__((ext_vector_type(8)));
typedef float f32x4 __attribute__((ext_vector_type(4)));

#define NB 256     // batch
#define TS 64      // timesteps
#define DD 1024    // input dim
#define HH 1024    // hidden
#define KTOT 3072  // D + 2H (fused GEMM K)
#define NOUT 4096  // 4H
#define KTILES 96  // KTOT/32
#define KSPLIT 3   // K-split factor (3 x 1024)
#define KT_PER 32  // ktiles per split
#define GITERS 16  // BK=64 iters per split
#define PSTRIDE (NB * NOUT)  // elems between preact partials

// ---------------------------------------------------------------------------
// Operand tile format: 16(rows/cols) x 32(k) fragment tiles of 512 bf16 (1KB).
// element (l, j):  row/col = base + (l&15),  k = kbase + (l>>4)*8 + j
// Matches mfma_f32_16x16x32_bf16 operand layout; global->LDS is a linear copy;
// ds_read_b128 is conflict-free.
// ---------------------------------------------------------------------------

static __device__ __forceinline__ void aop_store(bf16* __restrict__ Aop, int n, int k, float v) {
  const int mt = n >> 4;
  const int kt = k >> 5;
  const int off = (mt * KTILES + kt) * 512 + ((k >> 3) & 3) * 128 + (n & 15) * 8 + (k & 7);
  Aop[off] = (bf16)v;
}

// Convert [Wx; Wh; Wattn] (3072 x 4096 f32, stacked on K) into tiled bf16.
__global__ __launch_bounds__(256) void convert_w(const float* __restrict__ Wx,
                                                 const float* __restrict__ Wh,
                                                 const float* __restrict__ Wattn,
                                                 bf16* __restrict__ Wt) {
  const int gid = blockIdx.x * 256 + threadIdx.x;  // one 16B chunk per thread
  const int tile = gid >> 6;                       // 0..24575
  const int l = gid & 63;
  const int ntile = tile / KTILES;
  const int ktile = tile % KTILES;
  const int n = ntile * 16 + (l & 15);
  const int k0 = ktile * 32 + (l >> 4) * 8;
  bf16x8 ovec;
#pragma unroll
  for (int j = 0; j < 8; ++j) {
    const int k = k0 + j;
    float v;
    if (k < DD)            v = Wx[(size_t)k * NOUT + n];
    else if (k < DD + HH)  v = Wh[(size_t)(k - DD) * NOUT + n];
    else                   v = Wattn[(size_t)(k - DD - HH) * NOUT + n];
    ovec[j] = (bf16)v;
  }
  *(bf16x8*)(Wt + (size_t)tile * 512 + l * 8) = ovec;
}

// ---------------------------------------------------------------------------
// Attention over 16 positions + pack [xt | h | attn], 1 unit per thread
// (1024 threads / 16 waves). a[16] = A[n][u][:] stays in registers.
// Score reduction: split-tree (exchange + halve) = 32 shuffles, not 96.
// After 4 rounds lane holds position (lane&15); 2 more rounds full-wave sum.
// ---------------------------------------------------------------------------
static __device__ __forceinline__ void attn_pack_unit(
    int n, int u, float hn, const float a[16],
    const float* __restrict__ xt, bf16* __restrict__ Aop,
    float* __restrict__ red /*[256]*/, float* __restrict__ w_sh /*[16]*/) {
  const int lane = u & 63, wv = u >> 6;
  float s[16];
#pragma unroll
  for (int p = 0; p < 16; ++p) s[p] = hn * a[p];

#define RED_ROUND(r, cnt)                                              \
  {                                                                    \
    float tt[cnt];                                                     \
    _Pragma("unroll") for (int k = 0; k < cnt; ++k)                    \
        tt[k] = __shfl_xor(s[k], 1 << r, 64);                          \
    const bool sel = (lane >> r) & 1;                                  \
    _Pragma("unroll") for (int k = 0; k < cnt / 2; ++k) {              \
      const float sv = sel ? s[2 * k + 1] : s[2 * k];                  \
      const float tv = sel ? tt[2 * k + 1] : tt[2 * k];                \
      s[k] = sv + tv;                                                  \
    }                                                                  \
  }
  RED_ROUND(0, 16)
  RED_ROUND(1, 8)
  RED_ROUND(2, 4)
  RED_ROUND(3, 2)
#undef RED_ROUND
  s[0] += __shfl_xor(s[0], 16, 64);
  s[0] += __shfl_xor(s[0], 32, 64);
  if (lane < 16) red[wv * 16 + lane] = s[0];  // s[0] = score partial for p=lane&15
  __syncthreads();
  if (u < 16) {  // 16 lanes of wave 0: finish scores + softmax
    float tot = 0.f;
#pragma unroll
    for (int w = 0; w < 16; ++w) tot += red[w * 16 + u];
    tot *= 0.03125f;  // 1/sqrt(1024)
    float m = tot;
#pragma unroll
    for (int msk = 1; msk < 16; msk <<= 1) m = fmaxf(m, __shfl_xor(m, msk, 64));
    const float e = expf(tot - m);
    float sum = e;
#pragma unroll
    for (int msk = 1; msk < 16; msk <<= 1) sum += __shfl_xor(sum, msk, 64);
    w_sh[u] = e / sum;
  }
  __syncthreads();
  float av = 0.f;
#pragma unroll
  for (int p = 0; p < 16; ++p) av = fmaf(a[p], w_sh[p], av);
  aop_store(Aop, n, u, xt[u]);        // x_t
  aop_store(Aop, n, HH + u, hn);      // h
  aop_store(Aop, n, 2 * HH + u, av);  // attn
}

// h0 = mean(A, axis=(2,3)); c0 = h0; pack operand for step 0.
__global__ __launch_bounds__(1024, 4) void init_kernel(const float* __restrict__ A,
                                                       const float* __restrict__ x,
                                                       float* __restrict__ c_ws,
                                                       bf16* __restrict__ Aop) {
  __shared__ float red[256];
  __shared__ float w_sh[16];
  const int n = blockIdx.x, u = threadIdx.x;
  float a[16];
  const float* ar = A + ((size_t)n * HH + u) * 16;
#pragma unroll
  for (int p = 0; p < 16; ++p) a[p] = ar[p];
  float h0 = 0.f;
#pragma unroll
  for (int p = 0; p < 16; ++p) h0 += a[p];
  h0 *= 0.0625f;
  c_ws[n * HH + u] = h0;
  attn_pack_unit(n, u, h0, a, x + (size_t)n * TS * DD, Aop, red, w_sh);
}

// LSTM gates (+sum of K-split partials +bias) + output + next-step attn/pack.
__global__ __launch_bounds__(1024, 4) void cell_kernel(const float* __restrict__ preact,
                                                       const float* __restrict__ bias,
                                                       float* __restrict__ c_ws,
                                                       const float* __restrict__ A,
                                                       const float* __restrict__ x,
                                                       bf16* __restrict__ Aop,
                                                       float* __restrict__ out,
                                                       const int t) {
  __shared__ float red[256];
  __shared__ float w_sh[16];
  const int n = blockIdx.x, u = threadIdx.x;
  const float* pr = preact + (size_t)n * NOUT;
  const float ai = pr[u]          + pr[PSTRIDE + u]          + pr[2 * PSTRIDE + u]          + bias[u];
  const float af = pr[HH + u]     + pr[PSTRIDE + HH + u]     + pr[2 * PSTRIDE + HH + u]     + bias[HH + u];
  const float ao = pr[2 * HH + u] + pr[PSTRIDE + 2 * HH + u] + pr[2 * PSTRIDE + 2 * HH + u] + bias[2 * HH + u];
  const float ag = pr[3 * HH + u] + pr[PSTRIDE + 3 * HH + u] + pr[2 * PSTRIDE + 3 * HH + u] + bias[3 * HH + u];
  const float cold = c_ws[n * HH + u];
  const float si = 1.f / (1.f + expf(-ai));
  const float sf = 1.f / (1.f + expf(-af));
  const float so = 1.f / (1.f + expf(-ao));
  const float cn = sf * cold + si * tanhf(ag);
  const float hn = so * tanhf(cn);
  c_ws[n * HH + u] = cn;
  out[((size_t)n * TS + t) * HH + u] = hn;
  if (t == TS - 1) return;  // uniform exit
  float a[16];
  const float* ar = A + ((size_t)n * HH + u) * 16;
#pragma unroll
  for (int p = 0; p < 16; ++p) a[p] = ar[p];
  attn_pack_unit(n, u, hn, a, x + ((size_t)n * TS + (t + 1)) * DD, Aop, red, w_sh);
}

// preact_part[ks](256x4096) = Aop(:, ks*1024:+1024) @ Wt(slice), bf16 MFMA.
// 64x64 tile, 4 waves (2x2 of 32x32), BK=64, reg-staged LDS double buffer.
// K-split 3 -> 768 wgs -> 3 wg/CU -> 3 waves/SIMD (latency hiding).
__global__ __launch_bounds__(256) void gemm_kernel(const bf16* __restrict__ Aop,
                                                   const bf16* __restrict__ Wt,
                                                   float* __restrict__ preact) {
  __shared__ __align__(16) bf16 lds[2][16 * 512];  // 16 tiles x 1KB per buffer
  const int b = blockIdx.x;
  // XCD map: xcd = b&7 (round-robin dispatch heuristic). Each XCD keeps the
  // same 8 col-tiles across all rt and ks -> 3.1 MB weight slice stays in L2.
  const int xcd = b & 7, idx = b >> 3;          // idx in [0,96)
  const int rt = idx & 3;                       // row tile (64 rows)
  const int rest = idx >> 2;                    // [0,24)
  const int ct = xcd * 8 + (rest & 7);          // col tile (64 cols)
  const int ks = rest >> 3;                     // K-split index [0,3)
  const int tid = threadIdx.x;
  const int lane = tid & 63, wid = tid >> 6;
  const int wr = wid >> 1, wc = wid & 1;

  // staging: thread handles tile-slots s = wid + q*4; slot s<8: A, else B.
  const bf16* gsrc[4];
  int ldsoff[4];
#pragma unroll
  for (int q = 0; q < 4; ++q) {
    const int s = wid + q * 4;
    ldsoff[q] = s * 512 + lane * 8;
    if (s < 8) {
      const int mt = rt * 4 + (s >> 1);
      gsrc[q] = Aop + ((size_t)mt * KTILES + ks * KT_PER + (s & 1)) * 512 + lane * 8;
    } else {
      const int nt = ct * 4 + ((s - 8) >> 1);
      gsrc[q] = Wt + ((size_t)nt * KTILES + ks * KT_PER + (s & 1)) * 512 + lane * 8;
    }
  }

  f32x4 acc[2][2];
#pragma unroll
  for (int i = 0; i < 2; ++i)
#pragma unroll
    for (int j = 0; j < 2; ++j) acc[i][j] = (f32x4){0.f, 0.f, 0.f, 0.f};

  const int aoff0 = ((wr * 2 + 0) * 2) * 512 + lane * 8;
  const int aoff1 = ((wr * 2 + 1) * 2) * 512 + lane * 8;
  const int boff0 = (8 + (wc * 2 + 0) * 2) * 512 + lane * 8;
  const int boff1 = (8 + (wc * 2 + 1) * 2) * 512 + lane * 8;

  bf16x8 regs[4];
#pragma unroll
  for (int q = 0; q < 4; ++q) { regs[q] = *(const bf16x8*)gsrc[q]; gsrc[q] += 1024; }
#pragma unroll
  for (int q = 0; q < 4; ++q) *(bf16x8*)&lds[0][ldsoff[q]] = regs[q];

  for (int t = 0; t < GITERS; ++t) {
    __syncthreads();  // buf[t&1] writes visible to all waves
    if (t < GITERS - 1) {  // issue next-tile loads AFTER the barrier
#pragma unroll
      for (int q = 0; q < 4; ++q) { regs[q] = *(const bf16x8*)gsrc[q]; gsrc[q] += 1024; }
    }
    const bf16* buf = lds[t & 1];
#pragma unroll
    for (int kk = 0; kk < 2; ++kk) {
      const bf16x8 a0 = *(const bf16x8*)(buf + aoff0 + kk * 512);
      const bf16x8 a1 = *(const bf16x8*)(buf + aoff1 + kk * 512);
      const bf16x8 b0 = *(const bf16x8*)(buf + boff0 + kk * 512);
      const bf16x8 b1 = *(const bf16x8*)(buf + boff1 + kk * 512);
      acc[0][0] = __builtin_amdgcn_mfma_f32_16x16x32_bf16(a0, b0, acc[0][0], 0, 0, 0);
      acc[0][1] = __builtin_amdgcn_mfma_f32_16x16x32_bf16(a0, b1, acc[0][1], 0, 0, 0);
      acc[1][0] = __builtin_amdgcn_mfma_f32_16x16x32_bf16(a1, b0, acc[1][0], 0, 0, 0);
      acc[1][1] = __builtin_amdgcn_mfma_f32_16x16x32_bf16(a1, b1, acc[1][1], 0, 0, 0);
    }
    if (t < GITERS - 1) {
#pragma unroll
      for (int q = 0; q < 4; ++q) *(bf16x8*)&lds[(t + 1) & 1][ldsoff[q]] = regs[q];
    }
  }

  // epilogue: C/D layout col=lane&15, row=(lane>>4)*4+r  [m89-verified]
  float* pp = preact + (size_t)ks * PSTRIDE;
#pragma unroll
  for (int i = 0; i < 2; ++i) {
#pragma unroll
    for (int j = 0; j < 2; ++j) {
      const int row0 = rt * 64 + wr * 32 + i * 16 + (lane >> 4) * 4;
      const int col = ct * 64 + wc * 32 + j * 16 + (lane & 15);
#pragma unroll
      for (int r = 0; r < 4; ++r)
        pp[(size_t)(row0 + r) * NOUT + col] = acc[i][j][r];
    }
  }
}

// ---------------------------------------------------------------------------
// ws layout (bytes):
//   [0, 25165824)            Wt      bf16 tiled weights (3072x4096)
//   [25165824, 26738688)     Aop     bf16 tiled operand (256x3072)
//   [26738688, 39321600)     preact  f32 x3 K-split partials (256x4096 each)
//   [39321600, 40370176)     c       f32 (256x1024)
// total ~40.4 MB (poison fills show ws >= 256 MiB)
// ---------------------------------------------------------------------------
extern "C" void kernel_launch(void* const* d_in, const int* in_sizes, int n_in,
                              void* d_out, int out_size, void* d_ws, size_t ws_size,
                              hipStream_t stream) {
  const float* x     = (const float*)d_in[0];
  const float* A     = (const float*)d_in[1];
  const float* Wx    = (const float*)d_in[2];
  const float* Wh    = (const float*)d_in[3];
  const float* Wattn = (const float*)d_in[4];
  const float* bias  = (const float*)d_in[5];
  float* out = (float*)d_out;
  char* ws = (char*)d_ws;
  bf16* Wt      = (bf16*)(ws + 0);
  bf16* Aop     = (bf16*)(ws + 25165824);
  float* preact = (float*)(ws + 26738688);
  float* c_ws   = (float*)(ws + 39321600);

  convert_w<<<6144, 256, 0, stream>>>(Wx, Wh, Wattn, Wt);
  init_kernel<<<NB, 1024, 0, stream>>>(A, x, c_ws, Aop);
  for (int t = 0; t < TS; ++t) {
    gemm_kernel<<<NB * KSPLIT, 256, 0, stream>>>(Aop, Wt, preact);
    cell_kernel<<<NB, 1024, 0, stream>>>(preact, bias, c_ws, A, x, Aop, out, t);
  }
}

// Round 3
// 2108.812 us; speedup vs baseline: 1.2988x; 1.2357x over previous
//
#include <hip/hip_runtime.h>

typedef __bf16 bf16;
typedef bf16 bf16x8 __attribute__((ext_vector_type(8)));
typedef float f32x4 __attribute__((ext_vector_type(4)));

#define NB 256     // batch
#define TS 64      // timesteps
#define DD 1024    // input dim
#define HH 1024    // hidden
#define KTOT 3072  // D + 2H (fused GEMM K)
#define NOUT 4096  // 4H
#define KTILES 96  // KTOT/32
#define KSPLIT 3   // K-split factor (3 x 1024)
#define GITERS 16  // BK=64 iters per split
#define PSTRIDE (NB * NOUT)  // elems between preact partials

// Weights stay fragment-tiled (16n x 32k tiles of 512 bf16 = 1KB; element
// (l,j): n = base+(l&15), k = kbase+(l>>4)*8+j) -> linear LDS staging.
// The activation operand Aop is now PLAIN ROW-MAJOR (256 x 3072 bf16): the
// cell packs it with unit-stride stores; the GEMM gathers fragments via
// per-lane global addresses (LDS dest stays linear).

// Convert [Wx; Wh; Wattn] (3072 x 4096 f32, stacked on K) into tiled bf16.
__global__ __launch_bounds__(256) void convert_w(const float* __restrict__ Wx,
                                                 const float* __restrict__ Wh,
                                                 const float* __restrict__ Wattn,
                                                 bf16* __restrict__ Wt) {
  const int gid = blockIdx.x * 256 + threadIdx.x;  // one 16B chunk per thread
  const int tile = gid >> 6;                       // 0..24575
  const int l = gid & 63;
  const int ntile = tile / KTILES;
  const int ktile = tile % KTILES;
  const int n = ntile * 16 + (l & 15);
  const int k0 = ktile * 32 + (l >> 4) * 8;
  bf16x8 ovec;
#pragma unroll
  for (int j = 0; j < 8; ++j) {
    const int k = k0 + j;
    float v;
    if (k < DD)            v = Wx[(size_t)k * NOUT + n];
    else if (k < DD + HH)  v = Wh[(size_t)(k - DD) * NOUT + n];
    else                   v = Wattn[(size_t)(k - DD - HH) * NOUT + n];
    ovec[j] = (bf16)v;
  }
  *(bf16x8*)(Wt + (size_t)tile * 512 + l * 8) = ovec;
}

// Post-barrier tail shared by init/cell: scores -> softmax -> attn -> pack.
// Block = one n, 1024 threads (16 waves). h_sh[1024] already written.
// Wave w owns position p=w; lane accumulates over h = lane+64i; 5 ds_swizzle
// XOR butterflies reduce within each 32-lane half; two halves summed via LDS.
static __device__ __forceinline__ void attn_tail(
    int n, int u, const float* __restrict__ A, bf16* __restrict__ Aop,
    const float* __restrict__ h_sh, float* __restrict__ scA,
    float* __restrict__ scB) {
  const int lane = u & 63, w = u >> 6;
  const float* ap = A + (size_t)n * (HH * 16) + w;  // column p=w
  float s = 0.f;
#pragma unroll
  for (int i = 0; i < 16; ++i) {
    const int idx = lane + 64 * i;
    s = fmaf(h_sh[idx], ap[(size_t)idx * 16], s);
  }
  // register-only XOR reduce within each 32-lane half (ds_swizzle BitMode)
  s += __int_as_float(__builtin_amdgcn_ds_swizzle(__float_as_int(s), 0x041F));
  s += __int_as_float(__builtin_amdgcn_ds_swizzle(__float_as_int(s), 0x081F));
  s += __int_as_float(__builtin_amdgcn_ds_swizzle(__float_as_int(s), 0x101F));
  s += __int_as_float(__builtin_amdgcn_ds_swizzle(__float_as_int(s), 0x201F));
  s += __int_as_float(__builtin_amdgcn_ds_swizzle(__float_as_int(s), 0x401F));
  if (lane == 0) scA[w] = s;
  else if (lane == 32) scB[w] = s;
  __syncthreads();
  // softmax over 16 positions, computed redundantly per thread (all static
  // indices -> registers; kills a second barrier)
  float e[16];
  float m = -3.0e38f;
#pragma unroll
  for (int p = 0; p < 16; ++p) {
    e[p] = (scA[p] + scB[p]) * 0.03125f;  // 1/sqrt(1024)
    m = fmaxf(m, e[p]);
  }
  float sum = 0.f;
#pragma unroll
  for (int p = 0; p < 16; ++p) {
    e[p] = expf(e[p] - m);
    sum += e[p];
  }
  const float inv = 1.f / sum;
  const float* arow = A + (size_t)n * (HH * 16) + (size_t)u * 16;  // 64B contig
  float av = 0.f;
#pragma unroll
  for (int p = 0; p < 16; ++p) av = fmaf(arow[p], e[p], av);
  Aop[(size_t)n * KTOT + 2 * HH + u] = (bf16)(av * inv);
}

// h0 = mean(A, axis=(2,3)); c0 = h0; pack [x0 | h0 | attn0].
__global__ __launch_bounds__(1024) void init_kernel(const float* __restrict__ A,
                                                    const float* __restrict__ x,
                                                    float* __restrict__ c_ws,
                                                    bf16* __restrict__ Aop) {
  __shared__ float h_sh[HH];
  __shared__ float scA[16], scB[16];
  const int n = blockIdx.x, u = threadIdx.x;
  const float* arow = A + (size_t)n * (HH * 16) + (size_t)u * 16;
  float h0 = 0.f;
#pragma unroll
  for (int p = 0; p < 16; ++p) h0 += arow[p];
  h0 *= 0.0625f;
  c_ws[n * HH + u] = h0;
  h_sh[u] = h0;
  Aop[(size_t)n * KTOT + HH + u] = (bf16)h0;
  Aop[(size_t)n * KTOT + u] = (bf16)x[(size_t)n * TS * DD + u];
  __syncthreads();
  attn_tail(n, u, A, Aop, h_sh, scA, scB);
}

// LSTM gates (sum of K-split partials + bias) + output + next-step attn/pack.
__global__ __launch_bounds__(1024) void cell_kernel(const float* __restrict__ preact,
                                                    const float* __restrict__ bias,
                                                    float* __restrict__ c_ws,
                                                    const float* __restrict__ A,
                                                    const float* __restrict__ x,
                                                    bf16* __restrict__ Aop,
                                                    float* __restrict__ out,
                                                    const int t) {
  __shared__ float h_sh[HH];
  __shared__ float scA[16], scB[16];
  const int n = blockIdx.x, u = threadIdx.x;
  const float* pr = preact + (size_t)n * NOUT;
  const float ai = pr[u]          + pr[PSTRIDE + u]          + pr[2 * PSTRIDE + u]          + bias[u];
  const float af = pr[HH + u]     + pr[PSTRIDE + HH + u]     + pr[2 * PSTRIDE + HH + u]     + bias[HH + u];
  const float ao = pr[2 * HH + u] + pr[PSTRIDE + 2 * HH + u] + pr[2 * PSTRIDE + 2 * HH + u] + bias[2 * HH + u];
  const float ag = pr[3 * HH + u] + pr[PSTRIDE + 3 * HH + u] + pr[2 * PSTRIDE + 3 * HH + u] + bias[3 * HH + u];
  const float cold = c_ws[n * HH + u];
  const float si = 1.f / (1.f + expf(-ai));
  const float sf = 1.f / (1.f + expf(-af));
  const float so = 1.f / (1.f + expf(-ao));
  const float cn = sf * cold + si * tanhf(ag);
  const float hn = so * tanhf(cn);
  c_ws[n * HH + u] = cn;
  out[((size_t)n * TS + t) * HH + u] = hn;
  if (t == TS - 1) return;  // uniform: no next step to pack
  h_sh[u] = hn;
  Aop[(size_t)n * KTOT + HH + u] = (bf16)hn;
  Aop[(size_t)n * KTOT + u] = (bf16)x[((size_t)n * TS + t + 1) * DD + u];
  __syncthreads();
  attn_tail(n, u, A, Aop, h_sh, scA, scB);
}

// preact_part[ks](256x4096) = Aop(:, ks*1024:+1024) @ W(slice), bf16 MFMA.
// 64x64 tile, 4 waves (2x2 of 32x32), BK=64, reg-staged LDS double buffer.
// A gathered from row-major Aop via per-lane addresses; LDS stays linear.
__global__ __launch_bounds__(256) void gemm_kernel(const bf16* __restrict__ Aop,
                                                   const bf16* __restrict__ Wt,
                                                   float* __restrict__ preact) {
  __shared__ __align__(16) bf16 lds[2][16 * 512];  // 16 tiles x 1KB per buffer
  const int b = blockIdx.x;
  // XCD map: xcd = b&7; each XCD keeps the same 8 col-tiles across rt and ks
  // -> its 3.1 MB weight slice stays L2-resident across all 64 steps.
  const int xcd = b & 7, idx = b >> 3;          // idx in [0,96)
  const int rt = idx & 3;                       // row tile (64 rows)
  const int rest = idx >> 2;                    // [0,24)
  const int ct = xcd * 8 + (rest & 7);          // col tile (64 cols)
  const int ks = rest >> 3;                     // K-split index [0,3)
  const int tid = threadIdx.x;
  const int lane = tid & 63, wid = tid >> 6;
  const int wr = wid >> 1, wc = wid & 1;

  // staging: thread handles tile-slots s = wid + q*4; s<8: A, else B.
  const bf16* gsrc[4];
  int gstep[4], ldsoff[4];
#pragma unroll
  for (int q = 0; q < 4; ++q) {
    const int s = wid + q * 4;
    ldsoff[q] = s * 512 + lane * 8;
    if (s < 8) {
      const int row = rt * 64 + (s >> 1) * 16 + (lane & 15);
      const int k0 = ks * 1024 + (s & 1) * 32 + (lane >> 4) * 8;
      gsrc[q] = Aop + (size_t)row * KTOT + k0;
      gstep[q] = 64;  // BK per iter
    } else {
      const int nt = ct * 4 + ((s - 8) >> 1);
      gsrc[q] = Wt + ((size_t)nt * KTILES + ks * 32 + (s & 1)) * 512 + lane * 8;
      gstep[q] = 1024;  // 2 tiles per iter
    }
  }

  f32x4 acc[2][2];
#pragma unroll
  for (int i = 0; i < 2; ++i)
#pragma unroll
    for (int j = 0; j < 2; ++j) acc[i][j] = (f32x4){0.f, 0.f, 0.f, 0.f};

  const int aoff0 = ((wr * 2 + 0) * 2) * 512 + lane * 8;
  const int aoff1 = ((wr * 2 + 1) * 2) * 512 + lane * 8;
  const int boff0 = (8 + (wc * 2 + 0) * 2) * 512 + lane * 8;
  const int boff1 = (8 + (wc * 2 + 1) * 2) * 512 + lane * 8;

  bf16x8 regs[4];
#pragma unroll
  for (int q = 0; q < 4; ++q) { regs[q] = *(const bf16x8*)gsrc[q]; gsrc[q] += gstep[q]; }
#pragma unroll
  for (int q = 0; q < 4; ++q) *(bf16x8*)&lds[0][ldsoff[q]] = regs[q];

  for (int t = 0; t < GITERS; ++t) {
    __syncthreads();  // buf[t&1] writes visible to all waves
    if (t < GITERS - 1) {  // issue next-tile loads AFTER the barrier
#pragma unroll
      for (int q = 0; q < 4; ++q) { regs[q] = *(const bf16x8*)gsrc[q]; gsrc[q] += gstep[q]; }
    }
    const bf16* buf = lds[t & 1];
#pragma unroll
    for (int kk = 0; kk < 2; ++kk) {
      const bf16x8 a0 = *(const bf16x8*)(buf + aoff0 + kk * 512);
      const bf16x8 a1 = *(const bf16x8*)(buf + aoff1 + kk * 512);
      const bf16x8 b0 = *(const bf16x8*)(buf + boff0 + kk * 512);
      const bf16x8 b1 = *(const bf16x8*)(buf + boff1 + kk * 512);
      acc[0][0] = __builtin_amdgcn_mfma_f32_16x16x32_bf16(a0, b0, acc[0][0], 0, 0, 0);
      acc[0][1] = __builtin_amdgcn_mfma_f32_16x16x32_bf16(a0, b1, acc[0][1], 0, 0, 0);
      acc[1][0] = __builtin_amdgcn_mfma_f32_16x16x32_bf16(a1, b0, acc[1][0], 0, 0, 0);
      acc[1][1] = __builtin_amdgcn_mfma_f32_16x16x32_bf16(a1, b1, acc[1][1], 0, 0, 0);
    }
    if (t < GITERS - 1) {
#pragma unroll
      for (int q = 0; q < 4; ++q) *(bf16x8*)&lds[(t + 1) & 1][ldsoff[q]] = regs[q];
    }
  }

  // epilogue: C/D layout col=lane&15, row=(lane>>4)*4+r  [m89-verified]
  float* pp = preact + (size_t)ks * PSTRIDE;
#pragma unroll
  for (int i = 0; i < 2; ++i) {
#pragma unroll
    for (int j = 0; j < 2; ++j) {
      const int row0 = rt * 64 + wr * 32 + i * 16 + (lane >> 4) * 4;
      const int col = ct * 64 + wc * 32 + j * 16 + (lane & 15);
#pragma unroll
      for (int r = 0; r < 4; ++r)
        pp[(size_t)(row0 + r) * NOUT + col] = acc[i][j][r];
    }
  }
}

// ---------------------------------------------------------------------------
// ws layout (bytes):
//   [0, 25165824)            Wt      bf16 tiled weights (3072x4096)
//   [25165824, 26738688)     Aop     bf16 ROW-MAJOR operand (256x3072)
//   [26738688, 39321600)     preact  f32 x3 K-split partials (256x4096 each)
//   [39321600, 40370176)     c       f32 (256x1024)
// ---------------------------------------------------------------------------
extern "C" void kernel_launch(void* const* d_in, const int* in_sizes, int n_in,
                              void* d_out, int out_size, void* d_ws, size_t ws_size,
                              hipStream_t stream) {
  const float* x     = (const float*)d_in[0];
  const float* A     = (const float*)d_in[1];
  const float* Wx    = (const float*)d_in[2];
  const float* Wh    = (const float*)d_in[3];
  const float* Wattn = (const float*)d_in[4];
  const float* bias  = (const float*)d_in[5];
  float* out = (float*)d_out;
  char* ws = (char*)d_ws;
  bf16* Wt      = (bf16*)(ws + 0);
  bf16* Aop     = (bf16*)(ws + 25165824);
  float* preact = (float*)(ws + 26738688);
  float* c_ws   = (float*)(ws + 39321600);

  convert_w<<<6144, 256, 0, stream>>>(Wx, Wh, Wattn, Wt);
  init_kernel<<<NB, 1024, 0, stream>>>(A, x, c_ws, Aop);
  for (int t = 0; t < TS; ++t) {
    gemm_kernel<<<NB * KSPLIT, 256, 0, stream>>>(Aop, Wt, preact);
    cell_kernel<<<NB, 1024, 0, stream>>>(preact, bias, c_ws, A, x, Aop, out, t);
  }
}